// Round 14
// baseline (3748.587 us; speedup 1.0000x reference)
//
#include <hip/hip_runtime.h>

typedef __bf16 bf16;
typedef __bf16 bf16x8 __attribute__((ext_vector_type(8)));
typedef __bf16 bf16x4 __attribute__((ext_vector_type(4)));
typedef float  f32x4  __attribute__((ext_vector_type(4)));

#define DEV __device__ __forceinline__

// async global->LDS, 16B per lane; lds dest must be wave-uniform base (HW adds lane*16)
DEV void gload_lds16(const bf16* g, bf16* l) {
    __builtin_amdgcn_global_load_lds(
        (__attribute__((address_space(1))) void*)g,
        (__attribute__((address_space(3))) void*)l, 16, 0, 0);
}

// lgkmcnt(0) first: wave's own ds_reads complete before the barrier, so the
// next buffer-overwrite (gload_lds) can never race an in-flight read.
DEV void barrier_raw() {
    asm volatile("s_waitcnt lgkmcnt(0)" ::: "memory");
    __builtin_amdgcn_s_barrier();
    asm volatile("" ::: "memory");
}

enum { M_QKV, M_SCORES, M_PVRESID, M_RESID, M_GELU, M_OUT, M_WM, M_VMT };

// ---------------------------------------------------------------------------
// 128x128 tile GEMM: A+B in LDS, 3-buffer 2-ahead counted-vmcnt. LDS 48KB.
// C[m,n] = sum_k A[m,k]*B[n,k]; A:[M,K], B:[N,K] bf16 row-major.
// ---------------------------------------------------------------------------
template<int MODE>
__global__ __launch_bounds__(256)
void gemm_k(const bf16* __restrict__ A, const bf16* __restrict__ B,
            int M, int N, int K,
            long long batchA, long long batchB, long long batchC,
            const float* __restrict__ bias,
            bf16* __restrict__ Cb, float* __restrict__ Cf,
            bf16* __restrict__ qp, bf16* __restrict__ kp, bf16* __restrict__ vp)
{
    const int bm = blockIdx.x, bn = blockIdx.y, bz = blockIdx.z;
    const int kTiles = K >> 5;

    const int tid = threadIdx.x, wid = tid >> 6, lane = tid & 63;
    const bf16* Ab = A + (long long)bz * batchA + (long long)bm * 128 * K;
    const bf16* Bb = B + (long long)bz * batchB + (long long)bn * 128 * K;

    extern __shared__ __align__(16) bf16 smem[];   // 24576 elems = 48KB
    bf16* sA = smem;            // [3][4096]
    bf16* sB = smem + 12288;    // [3][4096]

    const int srow = wid * 16 + (lane >> 2);
    const int scol = (lane & 3) * 8;
    const long long aoff = (long long)srow * K + scol;

    auto stage = [&](int buf, int kt) {
        const bf16* ga = Ab + (long long)kt * 32;
        const bf16* gb = Bb + (long long)kt * 32;
        bf16* a = sA + buf * 4096;
        bf16* b = sB + buf * 4096;
        gload_lds16(ga + aoff,            a + (wid * 16) * 32);
        gload_lds16(ga + aoff + 64LL * K, a + (64 + wid * 16) * 32);
        gload_lds16(gb + aoff,            b + (wid * 16) * 32);
        gload_lds16(gb + aoff + 64LL * K, b + (64 + wid * 16) * 32);
    };

    f32x4 acc[4][4];
#pragma unroll
    for (int m = 0; m < 4; ++m)
#pragma unroll
        for (int n = 0; n < 4; ++n) acc[m][n] = (f32x4){0.f, 0.f, 0.f, 0.f};

    const int npre = kTiles < 2 ? kTiles : 2;
    for (int t = 0; t < npre; ++t) stage(t, t);

    const int wr = wid >> 1, wc = wid & 1;
    const int arow = wr * 64 + (lane & 15);
    const int brow = wc * 64 + (lane & 15);
    const int koff = (lane >> 4) * 8;

    int cur = 0;
    for (int kt = 0; kt < kTiles; ++kt) {
        if (kt + 1 < kTiles) asm volatile("s_waitcnt vmcnt(4)" ::: "memory");
        else                 asm volatile("s_waitcnt vmcnt(0)" ::: "memory");
        barrier_raw();
        if (kt + 2 < kTiles) {
            int ib = cur - 1; if (ib < 0) ib = 2;   // (cur+2)%3
            stage(ib, kt + 2);
        }

        const bf16* a = sA + cur * 4096;
        const bf16* b = sB + cur * 4096;
        bf16x8 af[4], bfr[4];
#pragma unroll
        for (int m = 0; m < 4; ++m)
            af[m] = *(const bf16x8*)&a[(arow + m * 16) * 32 + koff];
#pragma unroll
        for (int n = 0; n < 4; ++n)
            bfr[n] = *(const bf16x8*)&b[(brow + n * 16) * 32 + koff];
#pragma unroll
        for (int m = 0; m < 4; ++m)
#pragma unroll
            for (int n = 0; n < 4; ++n)
                acc[m][n] = __builtin_amdgcn_mfma_f32_16x16x32_bf16(af[m], bfr[n], acc[m][n], 0, 0, 0);

        cur = (cur == 2) ? 0 : cur + 1;
    }

    // C/D layout: col = lane&15, row = (lane>>4)*4 + r   [learn_hip m89]
    const int cr0 = bm * 128 + wr * 64 + (lane >> 4) * 4;
    const int cc0 = bn * 128 + wc * 64 + (lane & 15);
#pragma unroll
    for (int m = 0; m < 4; ++m) {
#pragma unroll
        for (int n = 0; n < 4; ++n) {
            const int col = cc0 + n * 16;
#pragma unroll
            for (int r = 0; r < 4; ++r) {
                const int row = cr0 + m * 16 + r;
                float v = acc[m][n][r];
                if (MODE == M_QKV) {
                    v += bias[col];
                    int hd = col / 192, rr = col % 192;
                    if (rr < 64)
                        qp[(long long)row * 768 + hd * 64 + rr] = (bf16)(v * 0.03608439182435161f);
                    else if (rr < 128)
                        kp[(long long)row * 768 + hd * 64 + (rr - 64)] = (bf16)v;
                    else  // v written STRAIGHT (coalesced); transpose happens in Vm epilogue
                        vp[(long long)row * 768 + hd * 64 + (rr - 128)] = (bf16)v;
                } else if (MODE == M_GELU) {
                    float xg = v + bias[col];
                    Cb[(long long)row * N + col] = (bf16)(xg / (1.f + __expf(-1.702f * xg)));
                } else if (MODE == M_RESID) {
                    long long idx = (long long)row * N + col;
                    Cf[idx] += v + bias[col];
                } else if (MODE == M_WM) {
                    Cb[(long long)bz * batchC + (long long)row * N + col] = (bf16)v;
                } else { // M_OUT (fp32 + bias)
                    Cf[(long long)row * N + col] = v + bias[col];
                }
            }
        }
    }
}

// ---------------------------------------------------------------------------
// 64x128 tile GEMM — 4-buffer 3-ahead counted-vmcnt, LDS 48KB -> 3 blocks/CU.
// Modes: PV+residual (causal trunc, h +=), plain residual, fp32 out.
// ---------------------------------------------------------------------------
template<int MODE>
__global__ __launch_bounds__(256)
void gemm64_k(const bf16* __restrict__ A, const bf16* __restrict__ B,
              int M, int N, int K,
              long long batchA, long long batchB, long long batchC,
              const float* __restrict__ bias,
              bf16* __restrict__ Cb, float* __restrict__ Cf)
{
    const int bm = blockIdx.x, bn = blockIdx.y, bz = blockIdx.z;
    int kTiles = K >> 5;
    if (MODE == M_PVRESID) {                         // P[:,k]==0 for k>row
        int lim = 2 * bm + 2;
        if (lim < kTiles) kTiles = lim;
    }

    const int tid = threadIdx.x, wid = tid >> 6, lane = tid & 63;
    const bf16* Ab = A + (long long)bz * batchA + (long long)bm * 64 * K;
    const bf16* Bb = B + (long long)bz * batchB + (long long)bn * 128 * K;

    extern __shared__ __align__(16) bf16 smem[];   // 24576 elems = 48KB
    bf16* sA = smem;            // [4][2048]
    bf16* sB = smem + 8192;     // [4][4096]

    const int srow = wid * 16 + (lane >> 2);          // 0..63
    const int scol = (lane & 3) * 8;
    const long long aoff = (long long)srow * K + scol;

    auto stage = [&](int buf, int kt) {
        const bf16* ga = Ab + (long long)kt * 32;
        const bf16* gb = Bb + (long long)kt * 32;
        gload_lds16(ga + aoff,            sA + buf * 2048 + (wid * 16) * 32);
        gload_lds16(gb + aoff,            sB + buf * 4096 + (wid * 16) * 32);
        gload_lds16(gb + aoff + 64LL * K, sB + buf * 4096 + (64 + wid * 16) * 32);
    };

    f32x4 acc[2][4];
#pragma unroll
    for (int m = 0; m < 2; ++m)
#pragma unroll
        for (int n = 0; n < 4; ++n) acc[m][n] = (f32x4){0.f, 0.f, 0.f, 0.f};

    const int npre = kTiles < 3 ? kTiles : 3;
    for (int t = 0; t < npre; ++t) stage(t, t);

    const int wr = wid >> 1, wc = wid & 1;
    const int arow = wr * 32 + (lane & 15);
    const int brow = wc * 64 + (lane & 15);
    const int koff = (lane >> 4) * 8;

    for (int kt = 0; kt < kTiles; ++kt) {
        const int rem = kTiles - 1 - kt;
        if (rem >= 2)      asm volatile("s_waitcnt vmcnt(6)" ::: "memory");
        else if (rem == 1) asm volatile("s_waitcnt vmcnt(3)" ::: "memory");
        else               asm volatile("s_waitcnt vmcnt(0)" ::: "memory");
        barrier_raw();
        if (kt + 3 < kTiles) stage((kt + 3) & 3, kt + 3);

        const int cur = kt & 3;
        const bf16* a = sA + cur * 2048;
        const bf16* b = sB + cur * 4096;
        bf16x8 af[2], bfr[4];
#pragma unroll
        for (int m = 0; m < 2; ++m)
            af[m] = *(const bf16x8*)&a[(arow + m * 16) * 32 + koff];
#pragma unroll
        for (int n = 0; n < 4; ++n)
            bfr[n] = *(const bf16x8*)&b[(brow + n * 16) * 32 + koff];
#pragma unroll
        for (int m = 0; m < 2; ++m)
#pragma unroll
            for (int n = 0; n < 4; ++n)
                acc[m][n] = __builtin_amdgcn_mfma_f32_16x16x32_bf16(af[m], bfr[n], acc[m][n], 0, 0, 0);
    }

    const int cr0 = bm * 64 + wr * 32 + (lane >> 4) * 4;
    const int cc0 = bn * 128 + wc * 64 + (lane & 15);
#pragma unroll
    for (int m = 0; m < 2; ++m) {
#pragma unroll
        for (int n = 0; n < 4; ++n) {
            const int col = cc0 + n * 16;
#pragma unroll
            for (int r = 0; r < 4; ++r) {
                const int row = cr0 + m * 16 + r;
                float v = acc[m][n][r];
                if (MODE == M_PVRESID) {
                    long long grow = (long long)bz * 1024 + row;
                    Cf[grow * 768 + col] += v + bias[col];
                } else if (MODE == M_RESID) {
                    long long idx = (long long)row * N + col;
                    Cf[idx] += v + bias[col];
                } else { // M_OUT (fp32 + bias)
                    Cf[(long long)row * N + col] = v + bias[col];
                }
            }
        }
    }
}

// ---------------------------------------------------------------------------
// Merged Vm + scores dispatch (both 64x128 tiles, K=768, kTiles=24 — data-
// independent, both depend only on qkv). One shared tail instead of two.
//   blocks [0,768):    Vm = V @ Wm^T  -> vmT[b, col, s]  (bm 0..127, bn 0..5)
//   blocks [768,1792): scores = Q @ K^T -> P              (bm 16, bn 8, bz 8)
// ---------------------------------------------------------------------------
__global__ __launch_bounds__(256)
void vm_scores_k(const bf16* __restrict__ vbuf, const bf16* __restrict__ wm,
                 const bf16* __restrict__ q, const bf16* __restrict__ kb,
                 bf16* __restrict__ vmT, bf16* __restrict__ P)
{
    const int bid = blockIdx.x;
    const bool isVm = bid < 768;
    const int K = 768, kTiles = 24;

    int bm, bn, bz = 0;
    const bf16 *Ab, *Bb;
    if (isVm) {
        bm = bid & 127; bn = bid >> 7;               // 128 x 6
        Ab = vbuf + (long long)bm * 64 * K;
        Bb = wm   + (long long)bn * 128 * K;
    } else {
        const int r = bid - 768;                     // 16 x 8 x 8
        bz = r >> 7;
        const int rr = r & 127;
        bm = rr >> 3; bn = rr & 7;
        if (2 * bn > bm) return;                     // fully-masked tile
        Ab = q  + (long long)bz * (1024LL * 768) + (long long)bm * 64 * K;
        Bb = kb + (long long)bz * (1024LL * 768) + (long long)bn * 128 * K;
    }

    const int tid = threadIdx.x, wid = tid >> 6, lane = tid & 63;

    extern __shared__ __align__(16) bf16 smem[];   // 24576 elems = 48KB
    bf16* sA = smem;            // [4][2048]
    bf16* sB = smem + 8192;     // [4][4096]

    const int srow = wid * 16 + (lane >> 2);
    const int scol = (lane & 3) * 8;
    const long long aoff = (long long)srow * K + scol;

    auto stage = [&](int buf, int kt) {
        const bf16* ga = Ab + (long long)kt * 32;
        const bf16* gb = Bb + (long long)kt * 32;
        gload_lds16(ga + aoff,            sA + buf * 2048 + (wid * 16) * 32);
        gload_lds16(gb + aoff,            sB + buf * 4096 + (wid * 16) * 32);
        gload_lds16(gb + aoff + 64LL * K, sB + buf * 4096 + (64 + wid * 16) * 32);
    };

    f32x4 acc[2][4];
#pragma unroll
    for (int m = 0; m < 2; ++m)
#pragma unroll
        for (int n = 0; n < 4; ++n) acc[m][n] = (f32x4){0.f, 0.f, 0.f, 0.f};

    stage(0, 0); stage(1, 1); stage(2, 2);

    const int wr = wid >> 1, wc = wid & 1;
    const int arow = wr * 32 + (lane & 15);
    const int brow = wc * 64 + (lane & 15);
    const int koff = (lane >> 4) * 8;

    for (int kt = 0; kt < kTiles; ++kt) {
        const int rem = kTiles - 1 - kt;
        if (rem >= 2)      asm volatile("s_waitcnt vmcnt(6)" ::: "memory");
        else if (rem == 1) asm volatile("s_waitcnt vmcnt(3)" ::: "memory");
        else               asm volatile("s_waitcnt vmcnt(0)" ::: "memory");
        barrier_raw();
        if (kt + 3 < kTiles) stage((kt + 3) & 3, kt + 3);

        const int cur = kt & 3;
        const bf16* a = sA + cur * 2048;
        const bf16* b = sB + cur * 4096;
        bf16x8 af[2], bfr[4];
#pragma unroll
        for (int m = 0; m < 2; ++m)
            af[m] = *(const bf16x8*)&a[(arow + m * 16) * 32 + koff];
#pragma unroll
        for (int n = 0; n < 4; ++n)
            bfr[n] = *(const bf16x8*)&b[(brow + n * 16) * 32 + koff];
#pragma unroll
        for (int m = 0; m < 2; ++m)
#pragma unroll
            for (int n = 0; n < 4; ++n)
                acc[m][n] = __builtin_amdgcn_mfma_f32_16x16x32_bf16(af[m], bfr[n], acc[m][n], 0, 0, 0);
    }

    const int cr0 = bm * 64 + wr * 32 + (lane >> 4) * 4;
    const int cc0 = bn * 128 + wc * 64 + (lane & 15);
#pragma unroll
    for (int m = 0; m < 2; ++m) {
#pragma unroll
        for (int n = 0; n < 4; ++n) {
            const int col = cc0 + n * 16;
#pragma unroll
            for (int r = 0; r < 4; ++r) {
                const int row = cr0 + m * 16 + r;
                float v = acc[m][n][r];
                if (isVm) {
                    long long b2 = row >> 10, s = row & 1023;
                    vmT[(b2 * 768 + col) * 1024 + s] = (bf16)v;
                } else {
                    P[(long long)bz * 1024 * 1024 + (long long)row * 1024 + col] = (bf16)v;
                }
            }
        }
    }
}

// ---------------------------------------------------------------------------
__global__ __launch_bounds__(256)
void cvt_bf16_k(const float* __restrict__ in, bf16* __restrict__ out, int n4)
{
    int i = blockIdx.x * 256 + threadIdx.x;
    if (i >= n4) return;
    float4 f = ((const float4*)in)[i];
    bf16x4 o = { (bf16)f.x, (bf16)f.y, (bf16)f.z, (bf16)f.w };
    ((bf16x4*)out)[i] = o;
}

// out[l][c][r] = (bf16) in[l][r][c]   (n x n per layer, n mult of 32)
__global__ __launch_bounds__(256)
void transpose_cvt_k(const float* __restrict__ in, bf16* __restrict__ out, int n)
{
    __shared__ float t[32][33];
    const int l = blockIdx.z;
    const int r0 = blockIdx.y * 32, c0 = blockIdx.x * 32;
    const float* src = in + (long long)l * n * n;
    bf16* dst = out + (long long)l * n * n;
    const int tx = threadIdx.x & 31, ty = threadIdx.x >> 5;   // 32x8
#pragma unroll
    for (int i = 0; i < 32; i += 8)
        t[ty + i][tx] = src[(long long)(r0 + ty + i) * n + c0 + tx];
    __syncthreads();
#pragma unroll
    for (int i = 0; i < 32; i += 8)
        dst[(long long)(c0 + ty + i) * n + r0 + tx] = (bf16)t[tx][ty + i];
}

// merged bias: bm[l][a] = sum_j o2w[l][a][j]*o1b[l][j] + o2b[l][a]; one wave per (l,a)
__global__ __launch_bounds__(256)
void bias_merge_k(const float* __restrict__ o2w, const float* __restrict__ o1b,
                  const float* __restrict__ o2b, float* __restrict__ bm, int total)
{
    const int wid = threadIdx.x >> 6, lane = threadIdx.x & 63;
    const int idx = blockIdx.x * 4 + wid;
    if (idx >= total) return;
    const int l = idx / 768, a = idx - l * 768;
    const float* wrow = o2w + ((long long)l * 768 + a) * 768;
    const float* brow = o1b + (long long)l * 768;
    float s = 0.f;
#pragma unroll
    for (int j = 0; j < 12; ++j) {
        int c = j * 64 + lane;
        s += wrow[c] * brow[c];
    }
#pragma unroll
    for (int o = 32; o; o >>= 1) s += __shfl_down(s, o);
    if (lane == 0) bm[idx] = s + o2b[(long long)l * 768 + a];
}

__global__ __launch_bounds__(256)
void cond_proj_k(const float* __restrict__ label, const float* __restrict__ sw,
                 const float* __restrict__ bw, float* __restrict__ scale,
                 float* __restrict__ bias, int total)
{
    int idx = blockIdx.x * 256 + threadIdx.x;
    if (idx >= total) return;
    int l = idx / 6144;
    int rem = idx - l * 6144;
    int b = rem / 768, d = rem - (rem / 768) * 768;
    const float* lab = label + b * 17;
    const float* swp = sw + ((long long)l * 768 + d) * 17;
    const float* bwp = bw + ((long long)l * 768 + d) * 17;
    float s = 0.f, bb = 0.f;
#pragma unroll
    for (int c = 0; c < 17; ++c) { float lv = lab[c]; s += lv * swp[c]; bb += lv * bwp[c]; }
    scale[idx] = s;
    bias[idx]  = bb;
}

// h[b,s,:] = (s==0 ? sos : xe[b,s-1,:]) + pos_bias(s)
__global__ __launch_bounds__(256)
void shift_pos_k(const float* __restrict__ xe, const float* __restrict__ sos,
                 const float* __restrict__ p0, const float* __restrict__ p1,
                 const float* __restrict__ p2, float* __restrict__ h)
{
    const int s = blockIdx.x, b = blockIdx.y;
    const int i0 = s >> 8, i1 = (s >> 4) & 15, i2 = s & 15;
    const float* xr = xe + ((long long)b * 1024 + (s - 1)) * 768;
#pragma unroll
    for (int j = 0; j < 3; ++j) {
        const int d = j * 256 + threadIdx.x;
        float v = (s == 0) ? sos[d] : xr[d];
        float pbv = (d < 256) ? p0[i0 * 256 + d]
                  : (d < 512) ? p1[i1 * 256 + (d - 256)]
                              : p2[i2 * 256 + (d - 512)];
        h[((long long)b * 1024 + s) * 768 + d] = v + pbv;
    }
}

// conditional LayerNorm — one WAVE per row (4 rows/block, shuffle-only).
__global__ __launch_bounds__(256)
void cond_ln_k(const float* __restrict__ h, const float* __restrict__ scale,
               const float* __restrict__ bias, bf16* __restrict__ out)
{
    const int wid = threadIdx.x >> 6, lane = threadIdx.x & 63;
    const int b = blockIdx.y;
    const long long row = (long long)b * 1024 + blockIdx.x * 4 + wid;
    const float4* hr4 = (const float4*)(h + row * 768);
    float4 v[3];
    float sum = 0.f, sq = 0.f;
#pragma unroll
    for (int j = 0; j < 3; ++j) {
        v[j] = hr4[j * 64 + lane];
        sum += v[j].x + v[j].y + v[j].z + v[j].w;
        sq  += v[j].x * v[j].x + v[j].y * v[j].y + v[j].z * v[j].z + v[j].w * v[j].w;
    }
#pragma unroll
    for (int o = 32; o; o >>= 1) { sum += __shfl_down(sum, o); sq += __shfl_down(sq, o); }
    sum = __shfl(sum, 0);
    sq  = __shfl(sq, 0);
    const float mean = sum * (1.f / 768.f);
    const float var  = sq * (1.f / 768.f) - mean * mean;
    const float rs   = rsqrtf(var + 1e-6f);
    const float4* sc4 = (const float4*)(scale + (long long)b * 768);
    const float4* bi4 = (const float4*)(bias  + (long long)b * 768);
    bf16x4* o4 = (bf16x4*)(out + row * 768);
#pragma unroll
    for (int j = 0; j < 3; ++j) {
        const float4 sc = sc4[j * 64 + lane];
        const float4 bi = bi4[j * 64 + lane];
        bf16x4 o = { (bf16)((v[j].x - mean) * rs * (1.f + sc.x) + bi.x),
                     (bf16)((v[j].y - mean) * rs * (1.f + sc.y) + bi.y),
                     (bf16)((v[j].z - mean) * rs * (1.f + sc.z) + bi.z),
                     (bf16)((v[j].w - mean) * rs * (1.f + sc.w) + bi.w) };
        o4[j * 64 + lane] = o;
    }
}

// causal softmax — one WAVE per row (4 rows/block, shuffle-only, vec4 I/O).
__global__ __launch_bounds__(256)
void softmax_k(bf16* __restrict__ P)
{
    const int wid = threadIdx.x >> 6, lane = threadIdx.x & 63;
    const int i = blockIdx.x * 4 + wid, b = blockIdx.y;
    bf16* row = P + ((long long)b * 1024 + i) * 1024;
    const int len = i + 1;
    const int lim = (i | 63) + 1;          // multiple of 64 -> vec4-aligned
    float v[4][4];
    float mx = -1e30f;
#pragma unroll
    for (int j = 0; j < 4; ++j) {
        const int c0 = (j * 64 + lane) * 4;
        bf16x4 pv = ((const bf16x4*)row)[j * 64 + lane];
#pragma unroll
        for (int e = 0; e < 4; ++e) {
            v[j][e] = (c0 + e < len) ? (float)pv[e] : -1e30f;
            mx = fmaxf(mx, v[j][e]);
        }
    }
#pragma unroll
    for (int o = 32; o; o >>= 1) mx = fmaxf(mx, __shfl_down(mx, o));
    mx = __shfl(mx, 0);
    float s = 0.f;
#pragma unroll
    for (int j = 0; j < 4; ++j)
#pragma unroll
        for (int e = 0; e < 4; ++e) {
            v[j][e] = __expf(v[j][e] - mx);   // exp(-1e30-mx)=0 for masked
            s += v[j][e];
        }
#pragma unroll
    for (int o = 32; o; o >>= 1) s += __shfl_down(s, o);
    s = __shfl(s, 0);
    const float inv = 1.f / s;
#pragma unroll
    for (int j = 0; j < 4; ++j) {
        const int c0 = (j * 64 + lane) * 4;
        if (c0 < lim) {
            bf16x4 o = { (bf16)(v[j][0] * inv), (bf16)(v[j][1] * inv),
                         (bf16)(v[j][2] * inv), (bf16)(v[j][3] * inv) };
            ((bf16x4*)row)[j * 64 + lane] = o;
        }
    }
}

__global__ __launch_bounds__(256)
void fill_k(float* o, int n, float v)
{
    int i = blockIdx.x * 256 + threadIdx.x;
    if (i < n) o[i] = v;
}

// ---------------------------------------------------------------------------
extern "C" void kernel_launch(void* const* d_in, const int* in_sizes, int n_in,
                              void* d_out, int out_size, void* d_ws, size_t ws_size,
                              hipStream_t stream)
{
    (void)in_sizes; (void)n_in;
    const float* x     = (const float*)d_in[0];
    const float* label = (const float*)d_in[2];
    const float* dw    = (const float*)d_in[3];
    const float* db    = (const float*)d_in[4];
    const float* sos   = (const float*)d_in[5];
    const float* p0    = (const float*)d_in[6];
    const float* p1    = (const float*)d_in[7];
    const float* p2    = (const float*)d_in[8];
    const float* ln1sw = (const float*)d_in[9];
    const float* ln1bw = (const float*)d_in[10];
    const float* qkvw  = (const float*)d_in[11];
    const float* qkvb  = (const float*)d_in[12];
    const float* ao1w  = (const float*)d_in[13];
    const float* ao1b  = (const float*)d_in[14];
    const float* ao2w  = (const float*)d_in[15];
    const float* ao2b  = (const float*)d_in[16];
    const float* ln2sw = (const float*)d_in[17];
    const float* ln2bw = (const float*)d_in[18];
    const float* m1w   = (const float*)d_in[19];
    const float* m1b   = (const float*)d_in[20];
    const float* m2w   = (const float*)d_in[21];
    const float* m2b   = (const float*)d_in[22];
    const float* lnfsw = (const float*)d_in[23];
    const float* lnfbw = (const float*)d_in[24];
    const float* outw  = (const float*)d_in[25];
    const float* outb  = (const float*)d_in[26];
    float* out = (float*)d_out;

    char* p = (char*)d_ws;
    auto alloc = [&](size_t bytes) { void* r = (void*)p; p += (bytes + 255) & ~(size_t)255; return r; };
    float* h    = (float*)alloc(8192LL * 768 * 4);
    bf16*  hn   = (bf16*) alloc(8192LL * 768 * 2);
    bf16*  q    = (bf16*) alloc(8192LL * 768 * 2);
    bf16*  kbuf = (bf16*) alloc(8192LL * 768 * 2);
    bf16*  vbuf = (bf16*) alloc(8192LL * 768 * 2);   // V straight [B*S, 768]
    bf16*  vmT  = (bf16*) alloc(8192LL * 768 * 2);   // (V@Wm^T)^T per batch [B,768,1024]
    bf16*  P    = (bf16*) alloc(8LL * 1024 * 1024 * 2);
    bf16*  mb   = (bf16*) alloc(8192LL * 3072 * 2);
    bf16*  wout = (bf16*) alloc(1024LL * 768 * 2);
    bf16*  wmA  = (bf16*) alloc(12LL * 768 * 768 * 2);   // merged o2@o1, bf16
    float* bmA  = (float*)alloc(12LL * 768 * 4);         // merged o-bias
    float* s1   = (float*)alloc(12LL * 8 * 768 * 4);
    float* b1   = (float*)alloc(12LL * 8 * 768 * 4);
    float* s2   = (float*)alloc(12LL * 8 * 768 * 4);
    float* b2   = (float*)alloc(12LL * 8 * 768 * 4);
    float* sf   = (float*)alloc(8LL * 768 * 4);
    float* bfb  = (float*)alloc(8LL * 768 * 4);

    size_t base_needed = (size_t)(p - (char*)d_ws);
    if (base_needed + 16LL * 1024 * 1024 > ws_size) {
        fill_k<<<(out_size + 255) / 256, 256, 0, stream>>>(out, out_size, 1e9f);
        return;
    }

    const long long SZ_QKV = 2304LL * 768, SZ_O = 768LL * 768, SZ_M = 3072LL * 768;
    size_t all_bytes = (size_t)(12 * (SZ_QKV + 2 * SZ_M)) * 2;
    bool allw = ((size_t)(p - (char*)d_ws) + all_bytes + 4096 <= ws_size);

    bf16 *wqkvA, *wm1A, *wm2A;
    if (allw) {
        wqkvA = (bf16*)alloc(12 * SZ_QKV * 2);
        wm1A  = (bf16*)alloc(12 * SZ_M * 2);
        wm2A  = (bf16*)alloc(12 * SZ_M * 2);
    } else {
        wqkvA = (bf16*)alloc(SZ_QKV * 2);
        wm1A  = (bf16*)alloc(SZ_M * 2);
        wm2A  = (bf16*)alloc(SZ_M * 2);
    }

    // one-time scratch aliased onto regions unused until the layer loop:
    bf16*  xbf   = (bf16*)P;
    bf16*  dwbf  = (bf16*)P + 524288;
    bf16*  wo2bf = (bf16*)P + 1048576;
    float* xe    = (float*)mb;
    bf16*  o1t   = mb + 12582912;

    // --- one-time precompute ---
    cvt_bf16_k<<<1024 * 768 / 4 / 256, 256, 0, stream>>>(outw, wout, 1024 * 768 / 4);
    cond_proj_k<<<(12 * 8 * 768 + 255) / 256, 256, 0, stream>>>(label, ln1sw, ln1bw, s1, b1, 12 * 8 * 768);
    cond_proj_k<<<(12 * 8 * 768 + 255) / 256, 256, 0, stream>>>(label, ln2sw, ln2bw, s2, b2, 12 * 8 * 768);
    cond_proj_k<<<(8 * 768 + 255) / 256, 256, 0, stream>>>(label, lnfsw, lnfbw, sf, bfb, 8 * 768);

    if (allw) {
        cvt_bf16_k<<<(int)(12 * SZ_QKV / 4 / 256), 256, 0, stream>>>(qkvw, wqkvA, (int)(12 * SZ_QKV / 4));
        cvt_bf16_k<<<(int)(12 * SZ_M / 4 / 256),   256, 0, stream>>>(m1w,  wm1A,  (int)(12 * SZ_M / 4));
        cvt_bf16_k<<<(int)(12 * SZ_M / 4 / 256),   256, 0, stream>>>(m2w,  wm2A,  (int)(12 * SZ_M / 4));
    }

    // merged out-proj: Wm[l] = o2[l] @ o1[l]  (bf16), bm[l] = o2[l]@o1b[l] + o2b[l]
    cvt_bf16_k<<<(int)(12 * SZ_O / 4 / 256), 256, 0, stream>>>(ao2w, wo2bf, (int)(12 * SZ_O / 4));
    transpose_cvt_k<<<dim3(24, 24, 12), 256, 0, stream>>>(ao1w, o1t, 768);
    gemm_k<M_WM><<<dim3(6, 6, 12), 256, 49152, stream>>>(
        wo2bf, o1t, 768, 768, 768, SZ_O, SZ_O, SZ_O,
        nullptr, wmA, nullptr, nullptr, nullptr, nullptr);
    bias_merge_k<<<(12 * 768 + 3) / 4, 256, 0, stream>>>(ao2w, ao1b, ao2b, bmA, 12 * 768);

    // embed: x->bf16, xe = x @ dw^T + db (fp32), then shift+pos
    cvt_bf16_k<<<8192 * 64 / 4 / 256, 256, 0, stream>>>(x, xbf, 8192 * 64 / 4);
    cvt_bf16_k<<<768 * 64 / 4 / 256, 256, 0, stream>>>(dw, dwbf, 768 * 64 / 4);
    gemm_k<M_OUT><<<dim3(64, 6, 1), 256, 49152, stream>>>(
        xbf, dwbf, 8192, 768, 64, 0, 0, 0, db, nullptr, xe, nullptr, nullptr, nullptr);
    shift_pos_k<<<dim3(1024, 8), 256, 0, stream>>>(xe, sos, p0, p1, p2, h);

    for (int l = 0; l < 12; ++l) {
        bf16 *wqkv, *wm1, *wm2;
        if (allw) {
            wqkv = wqkvA + (long long)l * SZ_QKV;
            wm1  = wm1A  + (long long)l * SZ_M;
            wm2  = wm2A  + (long long)l * SZ_M;
        } else {
            wqkv = wqkvA; wm1 = wm1A; wm2 = wm2A;
            cvt_bf16_k<<<(int)(SZ_QKV / 4 / 256), 256, 0, stream>>>(qkvw + (long long)l * SZ_QKV, wqkv, (int)(SZ_QKV / 4));
            cvt_bf16_k<<<(int)(SZ_M / 4 / 256),   256, 0, stream>>>(m1w  + (long long)l * SZ_M,   wm1,  (int)(SZ_M / 4));
            cvt_bf16_k<<<(int)(SZ_M / 4 / 256),   256, 0, stream>>>(m2w  + (long long)l * SZ_M,   wm2,  (int)(SZ_M / 4));
        }

        cond_ln_k<<<dim3(256, 8), 256, 0, stream>>>(h, s1 + (long long)l * 6144, b1 + (long long)l * 6144, hn);

        gemm_k<M_QKV><<<dim3(64, 18, 1), 256, 49152, stream>>>(
            hn, wqkv, 8192, 2304, 768, 0, 0, 0,
            qkvb + (long long)l * 2304, nullptr, nullptr, q, kbuf, vbuf);

        // Vm = V@Wm^T and scores = Q@K^T are independent -> single dispatch
        vm_scores_k<<<1792, 256, 49152, stream>>>(
            vbuf, wmA + (long long)l * SZ_O, q, kbuf, vmT, P);

        softmax_k<<<dim3(256, 8), 256, 0, stream>>>(P);

        // h += P @ Vm + bm   (attn output + merged out-proj + residual, fused)
        gemm64_k<M_PVRESID><<<dim3(16, 6, 8), 256, 49152, stream>>>(
            P, vmT, 1024, 768, 1024, 1024LL * 1024, 768LL * 1024, 0,
            bmA + (long long)l * 768, nullptr, h);

        cond_ln_k<<<dim3(256, 8), 256, 0, stream>>>(h, s2 + (long long)l * 6144, b2 + (long long)l * 6144, hn);

        gemm_k<M_GELU><<<dim3(64, 24, 1), 256, 49152, stream>>>(
            hn, wm1, 8192, 3072, 768, 0, 0, 0,
            m1b + (long long)l * 3072, mb, nullptr, nullptr, nullptr, nullptr);

        gemm64_k<M_RESID><<<dim3(128, 6, 1), 256, 49152, stream>>>(
            mb, wm2, 8192, 768, 3072, 0, 0, 0,
            m2b + (long long)l * 768, nullptr, h);
    }

    cond_ln_k<<<dim3(256, 8), 256, 0, stream>>>(h, sf, bfb, hn);
    gemm64_k<M_OUT><<<dim3(128, 8, 1), 256, 49152, stream>>>(
        hn, wout, 8192, 1024, 768, 0, 0, 0,
        outb, nullptr, out);
}

// Round 15
// 3718.332 us; speedup vs baseline: 1.0081x; 1.0081x over previous
//
#include <hip/hip_runtime.h>

typedef __bf16 bf16;
typedef __bf16 bf16x8 __attribute__((ext_vector_type(8)));
typedef __bf16 bf16x4 __attribute__((ext_vector_type(4)));
typedef float  f32x4  __attribute__((ext_vector_type(4)));

#define DEV __device__ __forceinline__

// async global->LDS, 16B per lane; lds dest must be wave-uniform base (HW adds lane*16)
DEV void gload_lds16(const bf16* g, bf16* l) {
    __builtin_amdgcn_global_load_lds(
        (__attribute__((address_space(1))) void*)g,
        (__attribute__((address_space(3))) void*)l, 16, 0, 0);
}

// lgkmcnt(0) first: wave's own ds_reads complete before the barrier, so the
// next buffer-overwrite (gload_lds) can never race an in-flight read.
DEV void barrier_raw() {
    asm volatile("s_waitcnt lgkmcnt(0)" ::: "memory");
    __builtin_amdgcn_s_barrier();
    asm volatile("" ::: "memory");
}

enum { M_QKV, M_SCORES, M_PVRESID, M_RESID, M_GELU, M_OUT, M_WM, M_VMT };

// ---------------------------------------------------------------------------
// 128x128 tile GEMM: A+B in LDS, 3-buffer 2-ahead counted-vmcnt. LDS 48KB.
// C[m,n] = sum_k A[m,k]*B[n,k]; A:[M,K], B:[N,K] bf16 row-major.
// ---------------------------------------------------------------------------
template<int MODE>
__global__ __launch_bounds__(256)
void gemm_k(const bf16* __restrict__ A, const bf16* __restrict__ B,
            int M, int N, int K,
            long long batchA, long long batchB, long long batchC,
            const float* __restrict__ bias,
            bf16* __restrict__ Cb, float* __restrict__ Cf,
            bf16* __restrict__ qp, bf16* __restrict__ kp, bf16* __restrict__ vp)
{
    const int bm = blockIdx.x, bn = blockIdx.y, bz = blockIdx.z;
    const int kTiles = K >> 5;

    const int tid = threadIdx.x, wid = tid >> 6, lane = tid & 63;
    const bf16* Ab = A + (long long)bz * batchA + (long long)bm * 128 * K;
    const bf16* Bb = B + (long long)bz * batchB + (long long)bn * 128 * K;

    extern __shared__ __align__(16) bf16 smem[];   // 24576 elems = 48KB
    bf16* sA = smem;            // [3][4096]
    bf16* sB = smem + 12288;    // [3][4096]

    const int srow = wid * 16 + (lane >> 2);
    const int scol = (lane & 3) * 8;
    const long long aoff = (long long)srow * K + scol;

    auto stage = [&](int buf, int kt) {
        const bf16* ga = Ab + (long long)kt * 32;
        const bf16* gb = Bb + (long long)kt * 32;
        bf16* a = sA + buf * 4096;
        bf16* b = sB + buf * 4096;
        gload_lds16(ga + aoff,            a + (wid * 16) * 32);
        gload_lds16(ga + aoff + 64LL * K, a + (64 + wid * 16) * 32);
        gload_lds16(gb + aoff,            b + (wid * 16) * 32);
        gload_lds16(gb + aoff + 64LL * K, b + (64 + wid * 16) * 32);
    };

    f32x4 acc[4][4];
#pragma unroll
    for (int m = 0; m < 4; ++m)
#pragma unroll
        for (int n = 0; n < 4; ++n) acc[m][n] = (f32x4){0.f, 0.f, 0.f, 0.f};

    const int npre = kTiles < 2 ? kTiles : 2;
    for (int t = 0; t < npre; ++t) stage(t, t);

    const int wr = wid >> 1, wc = wid & 1;
    const int arow = wr * 64 + (lane & 15);
    const int brow = wc * 64 + (lane & 15);
    const int koff = (lane >> 4) * 8;

    int cur = 0;
    for (int kt = 0; kt < kTiles; ++kt) {
        if (kt + 1 < kTiles) asm volatile("s_waitcnt vmcnt(4)" ::: "memory");
        else                 asm volatile("s_waitcnt vmcnt(0)" ::: "memory");
        barrier_raw();
        if (kt + 2 < kTiles) {
            int ib = cur - 1; if (ib < 0) ib = 2;   // (cur+2)%3
            stage(ib, kt + 2);
        }

        const bf16* a = sA + cur * 4096;
        const bf16* b = sB + cur * 4096;
        bf16x8 af[4], bfr[4];
#pragma unroll
        for (int m = 0; m < 4; ++m)
            af[m] = *(const bf16x8*)&a[(arow + m * 16) * 32 + koff];
#pragma unroll
        for (int n = 0; n < 4; ++n)
            bfr[n] = *(const bf16x8*)&b[(brow + n * 16) * 32 + koff];
#pragma unroll
        for (int m = 0; m < 4; ++m)
#pragma unroll
            for (int n = 0; n < 4; ++n)
                acc[m][n] = __builtin_amdgcn_mfma_f32_16x16x32_bf16(af[m], bfr[n], acc[m][n], 0, 0, 0);

        cur = (cur == 2) ? 0 : cur + 1;
    }

    // C/D layout: col = lane&15, row = (lane>>4)*4 + r   [learn_hip m89]
    const int cr0 = bm * 128 + wr * 64 + (lane >> 4) * 4;
    const int cc0 = bn * 128 + wc * 64 + (lane & 15);
#pragma unroll
    for (int m = 0; m < 4; ++m) {
#pragma unroll
        for (int n = 0; n < 4; ++n) {
            const int col = cc0 + n * 16;
#pragma unroll
            for (int r = 0; r < 4; ++r) {
                const int row = cr0 + m * 16 + r;
                float v = acc[m][n][r];
                if (MODE == M_QKV) {
                    v += bias[col];
                    int hd = col / 192, rr = col % 192;
                    if (rr < 64)
                        qp[(long long)row * 768 + hd * 64 + rr] = (bf16)(v * 0.03608439182435161f);
                    else if (rr < 128)
                        kp[(long long)row * 768 + hd * 64 + (rr - 64)] = (bf16)v;
                    else  // v written STRAIGHT (coalesced); transpose happens in Vm epilogue
                        vp[(long long)row * 768 + hd * 64 + (rr - 128)] = (bf16)v;
                } else if (MODE == M_GELU) {
                    float xg = v + bias[col];
                    Cb[(long long)row * N + col] = (bf16)(xg / (1.f + __expf(-1.702f * xg)));
                } else if (MODE == M_RESID) {
                    long long idx = (long long)row * N + col;
                    Cf[idx] += v + bias[col];
                } else if (MODE == M_WM) {
                    Cb[(long long)bz * batchC + (long long)row * N + col] = (bf16)v;
                } else { // M_OUT (fp32 + bias)
                    Cf[(long long)row * N + col] = v + bias[col];
                }
            }
        }
    }
}

// ---------------------------------------------------------------------------
// 64x128 tile GEMM — 4-buffer 3-ahead counted-vmcnt, LDS 48KB -> 3 blocks/CU.
// Modes: scores (causal skip), PV+residual (causal trunc, h +=), Vm
// (transposed scatter), plain residual, fp32 out.
// ---------------------------------------------------------------------------
template<int MODE>
__global__ __launch_bounds__(256)
void gemm64_k(const bf16* __restrict__ A, const bf16* __restrict__ B,
              int M, int N, int K,
              long long batchA, long long batchB, long long batchC,
              const float* __restrict__ bias,
              bf16* __restrict__ Cb, float* __restrict__ Cf)
{
    const int bm = blockIdx.x, bn = blockIdx.y, bz = blockIdx.z;
    if (MODE == M_SCORES && 2 * bn > bm) return;     // fully-masked tile
    int kTiles = K >> 5;
    if (MODE == M_PVRESID) {                         // P[:,k]==0 for k>row
        int lim = 2 * bm + 2;
        if (lim < kTiles) kTiles = lim;
    }

    const int tid = threadIdx.x, wid = tid >> 6, lane = tid & 63;
    const bf16* Ab = A + (long long)bz * batchA + (long long)bm * 64 * K;
    const bf16* Bb = B + (long long)bz * batchB + (long long)bn * 128 * K;

    extern __shared__ __align__(16) bf16 smem[];   // 24576 elems = 48KB
    bf16* sA = smem;            // [4][2048]
    bf16* sB = smem + 8192;     // [4][4096]

    const int srow = wid * 16 + (lane >> 2);          // 0..63
    const int scol = (lane & 3) * 8;
    const long long aoff = (long long)srow * K + scol;

    auto stage = [&](int buf, int kt) {
        const bf16* ga = Ab + (long long)kt * 32;
        const bf16* gb = Bb + (long long)kt * 32;
        gload_lds16(ga + aoff,            sA + buf * 2048 + (wid * 16) * 32);
        gload_lds16(gb + aoff,            sB + buf * 4096 + (wid * 16) * 32);
        gload_lds16(gb + aoff + 64LL * K, sB + buf * 4096 + (64 + wid * 16) * 32);
    };

    f32x4 acc[2][4];
#pragma unroll
    for (int m = 0; m < 2; ++m)
#pragma unroll
        for (int n = 0; n < 4; ++n) acc[m][n] = (f32x4){0.f, 0.f, 0.f, 0.f};

    const int npre = kTiles < 3 ? kTiles : 3;
    for (int t = 0; t < npre; ++t) stage(t, t);

    const int wr = wid >> 1, wc = wid & 1;
    const int arow = wr * 32 + (lane & 15);
    const int brow = wc * 64 + (lane & 15);
    const int koff = (lane >> 4) * 8;

    for (int kt = 0; kt < kTiles; ++kt) {
        const int rem = kTiles - 1 - kt;
        if (rem >= 2)      asm volatile("s_waitcnt vmcnt(6)" ::: "memory");
        else if (rem == 1) asm volatile("s_waitcnt vmcnt(3)" ::: "memory");
        else               asm volatile("s_waitcnt vmcnt(0)" ::: "memory");
        barrier_raw();
        if (kt + 3 < kTiles) stage((kt + 3) & 3, kt + 3);

        const int cur = kt & 3;
        const bf16* a = sA + cur * 2048;
        const bf16* b = sB + cur * 4096;
        bf16x8 af[2], bfr[4];
#pragma unroll
        for (int m = 0; m < 2; ++m)
            af[m] = *(const bf16x8*)&a[(arow + m * 16) * 32 + koff];
#pragma unroll
        for (int n = 0; n < 4; ++n)
            bfr[n] = *(const bf16x8*)&b[(brow + n * 16) * 32 + koff];
#pragma unroll
        for (int m = 0; m < 2; ++m)
#pragma unroll
            for (int n = 0; n < 4; ++n)
                acc[m][n] = __builtin_amdgcn_mfma_f32_16x16x32_bf16(af[m], bfr[n], acc[m][n], 0, 0, 0);
    }

    const int cr0 = bm * 64 + wr * 32 + (lane >> 4) * 4;
    const int cc0 = bn * 128 + wc * 64 + (lane & 15);
#pragma unroll
    for (int m = 0; m < 2; ++m) {
#pragma unroll
        for (int n = 0; n < 4; ++n) {
            const int col = cc0 + n * 16;
#pragma unroll
            for (int r = 0; r < 4; ++r) {
                const int row = cr0 + m * 16 + r;
                float v = acc[m][n][r];
                if (MODE == M_SCORES) {
                    Cb[(long long)bz * batchC + (long long)row * N + col] = (bf16)v;
                } else if (MODE == M_PVRESID) {
                    long long grow = (long long)bz * 1024 + row;
                    Cf[grow * 768 + col] += v + bias[col];
                } else if (MODE == M_VMT) {
                    // Vm = V @ Wm^T, stored transposed per batch: vmT[b, col, s]
                    long long b2 = row >> 10, s = row & 1023;
                    Cb[(b2 * 768 + col) * 1024 + s] = (bf16)v;
                } else if (MODE == M_RESID) {
                    long long idx = (long long)row * N + col;
                    Cf[idx] += v + bias[col];
                } else { // M_OUT (fp32 + bias)
                    Cf[(long long)row * N + col] = v + bias[col];
                }
            }
        }
    }
}

// ---------------------------------------------------------------------------
__global__ __launch_bounds__(256)
void cvt_bf16_k(const float* __restrict__ in, bf16* __restrict__ out, int n4)
{
    int i = blockIdx.x * 256 + threadIdx.x;
    if (i >= n4) return;
    float4 f = ((const float4*)in)[i];
    bf16x4 o = { (bf16)f.x, (bf16)f.y, (bf16)f.z, (bf16)f.w };
    ((bf16x4*)out)[i] = o;
}

// out[l][c][r] = (bf16) in[l][r][c]   (n x n per layer, n mult of 32)
__global__ __launch_bounds__(256)
void transpose_cvt_k(const float* __restrict__ in, bf16* __restrict__ out, int n)
{
    __shared__ float t[32][33];
    const int l = blockIdx.z;
    const int r0 = blockIdx.y * 32, c0 = blockIdx.x * 32;
    const float* src = in + (long long)l * n * n;
    bf16* dst = out + (long long)l * n * n;
    const int tx = threadIdx.x & 31, ty = threadIdx.x >> 5;   // 32x8
#pragma unroll
    for (int i = 0; i < 32; i += 8)
        t[ty + i][tx] = src[(long long)(r0 + ty + i) * n + c0 + tx];
    __syncthreads();
#pragma unroll
    for (int i = 0; i < 32; i += 8)
        dst[(long long)(c0 + ty + i) * n + r0 + tx] = (bf16)t[tx][ty + i];
}

// merged bias: bm[l][a] = sum_j o2w[l][a][j]*o1b[l][j] + o2b[l][a]; one wave per (l,a)
__global__ __launch_bounds__(256)
void bias_merge_k(const float* __restrict__ o2w, const float* __restrict__ o1b,
                  const float* __restrict__ o2b, float* __restrict__ bm, int total)
{
    const int wid = threadIdx.x >> 6, lane = threadIdx.x & 63;
    const int idx = blockIdx.x * 4 + wid;
    if (idx >= total) return;
    const int l = idx / 768, a = idx - l * 768;
    const float* wrow = o2w + ((long long)l * 768 + a) * 768;
    const float* brow = o1b + (long long)l * 768;
    float s = 0.f;
#pragma unroll
    for (int j = 0; j < 12; ++j) {
        int c = j * 64 + lane;
        s += wrow[c] * brow[c];
    }
#pragma unroll
    for (int o = 32; o; o >>= 1) s += __shfl_down(s, o);
    if (lane == 0) bm[idx] = s + o2b[(long long)l * 768 + a];
}

__global__ __launch_bounds__(256)
void cond_proj_k(const float* __restrict__ label, const float* __restrict__ sw,
                 const float* __restrict__ bw, float* __restrict__ scale,
                 float* __restrict__ bias, int total)
{
    int idx = blockIdx.x * 256 + threadIdx.x;
    if (idx >= total) return;
    int l = idx / 6144;
    int rem = idx - l * 6144;
    int b = rem / 768, d = rem - (rem / 768) * 768;
    const float* lab = label + b * 17;
    const float* swp = sw + ((long long)l * 768 + d) * 17;
    const float* bwp = bw + ((long long)l * 768 + d) * 17;
    float s = 0.f, bb = 0.f;
#pragma unroll
    for (int c = 0; c < 17; ++c) { float lv = lab[c]; s += lv * swp[c]; bb += lv * bwp[c]; }
    scale[idx] = s;
    bias[idx]  = bb;
}

// h[b,s,:] = (s==0 ? sos : xe[b,s-1,:]) + pos_bias(s)
__global__ __launch_bounds__(256)
void shift_pos_k(const float* __restrict__ xe, const float* __restrict__ sos,
                 const float* __restrict__ p0, const float* __restrict__ p1,
                 const float* __restrict__ p2, float* __restrict__ h)
{
    const int s = blockIdx.x, b = blockIdx.y;
    const int i0 = s >> 8, i1 = (s >> 4) & 15, i2 = s & 15;
    const float* xr = xe + ((long long)b * 1024 + (s - 1)) * 768;
#pragma unroll
    for (int j = 0; j < 3; ++j) {
        const int d = j * 256 + threadIdx.x;
        float v = (s == 0) ? sos[d] : xr[d];
        float pbv = (d < 256) ? p0[i0 * 256 + d]
                  : (d < 512) ? p1[i1 * 256 + (d - 256)]
                              : p2[i2 * 256 + (d - 512)];
        h[((long long)b * 1024 + s) * 768 + d] = v + pbv;
    }
}

// conditional LayerNorm — one WAVE per row (4 rows/block, shuffle-only).
__global__ __launch_bounds__(256)
void cond_ln_k(const float* __restrict__ h, const float* __restrict__ scale,
               const float* __restrict__ bias, bf16* __restrict__ out)
{
    const int wid = threadIdx.x >> 6, lane = threadIdx.x & 63;
    const int b = blockIdx.y;
    const long long row = (long long)b * 1024 + blockIdx.x * 4 + wid;
    const float4* hr4 = (const float4*)(h + row * 768);
    float4 v[3];
    float sum = 0.f, sq = 0.f;
#pragma unroll
    for (int j = 0; j < 3; ++j) {
        v[j] = hr4[j * 64 + lane];
        sum += v[j].x + v[j].y + v[j].z + v[j].w;
        sq  += v[j].x * v[j].x + v[j].y * v[j].y + v[j].z * v[j].z + v[j].w * v[j].w;
    }
#pragma unroll
    for (int o = 32; o; o >>= 1) { sum += __shfl_down(sum, o); sq += __shfl_down(sq, o); }
    sum = __shfl(sum, 0);
    sq  = __shfl(sq, 0);
    const float mean = sum * (1.f / 768.f);
    const float var  = sq * (1.f / 768.f) - mean * mean;
    const float rs   = rsqrtf(var + 1e-6f);
    const float4* sc4 = (const float4*)(scale + (long long)b * 768);
    const float4* bi4 = (const float4*)(bias  + (long long)b * 768);
    bf16x4* o4 = (bf16x4*)(out + row * 768);
#pragma unroll
    for (int j = 0; j < 3; ++j) {
        const float4 sc = sc4[j * 64 + lane];
        const float4 bi = bi4[j * 64 + lane];
        bf16x4 o = { (bf16)((v[j].x - mean) * rs * (1.f + sc.x) + bi.x),
                     (bf16)((v[j].y - mean) * rs * (1.f + sc.y) + bi.y),
                     (bf16)((v[j].z - mean) * rs * (1.f + sc.z) + bi.z),
                     (bf16)((v[j].w - mean) * rs * (1.f + sc.w) + bi.w) };
        o4[j * 64 + lane] = o;
    }
}

// causal softmax — one WAVE per row (4 rows/block, shuffle-only, vec4 I/O).
__global__ __launch_bounds__(256)
void softmax_k(bf16* __restrict__ P)
{
    const int wid = threadIdx.x >> 6, lane = threadIdx.x & 63;
    const int i = blockIdx.x * 4 + wid, b = blockIdx.y;
    bf16* row = P + ((long long)b * 1024 + i) * 1024;
    const int len = i + 1;
    const int lim = (i | 63) + 1;          // multiple of 64 -> vec4-aligned
    float v[4][4];
    float mx = -1e30f;
#pragma unroll
    for (int j = 0; j < 4; ++j) {
        const int c0 = (j * 64 + lane) * 4;
        bf16x4 pv = ((const bf16x4*)row)[j * 64 + lane];
#pragma unroll
        for (int e = 0; e < 4; ++e) {
            v[j][e] = (c0 + e < len) ? (float)pv[e] : -1e30f;
            mx = fmaxf(mx, v[j][e]);
        }
    }
#pragma unroll
    for (int o = 32; o; o >>= 1) mx = fmaxf(mx, __shfl_down(mx, o));
    mx = __shfl(mx, 0);
    float s = 0.f;
#pragma unroll
    for (int j = 0; j < 4; ++j)
#pragma unroll
        for (int e = 0; e < 4; ++e) {
            v[j][e] = __expf(v[j][e] - mx);   // exp(-1e30-mx)=0 for masked
            s += v[j][e];
        }
#pragma unroll
    for (int o = 32; o; o >>= 1) s += __shfl_down(s, o);
    s = __shfl(s, 0);
    const float inv = 1.f / s;
#pragma unroll
    for (int j = 0; j < 4; ++j) {
        const int c0 = (j * 64 + lane) * 4;
        if (c0 < lim) {
            bf16x4 o = { (bf16)(v[j][0] * inv), (bf16)(v[j][1] * inv),
                         (bf16)(v[j][2] * inv), (bf16)(v[j][3] * inv) };
            ((bf16x4*)row)[j * 64 + lane] = o;
        }
    }
}

__global__ __launch_bounds__(256)
void fill_k(float* o, int n, float v)
{
    int i = blockIdx.x * 256 + threadIdx.x;
    if (i < n) o[i] = v;
}

// ---------------------------------------------------------------------------
extern "C" void kernel_launch(void* const* d_in, const int* in_sizes, int n_in,
                              void* d_out, int out_size, void* d_ws, size_t ws_size,
                              hipStream_t stream)
{
    (void)in_sizes; (void)n_in;
    const float* x     = (const float*)d_in[0];
    const float* label = (const float*)d_in[2];
    const float* dw    = (const float*)d_in[3];
    const float* db    = (const float*)d_in[4];
    const float* sos   = (const float*)d_in[5];
    const float* p0    = (const float*)d_in[6];
    const float* p1    = (const float*)d_in[7];
    const float* p2    = (const float*)d_in[8];
    const float* ln1sw = (const float*)d_in[9];
    const float* ln1bw = (const float*)d_in[10];
    const float* qkvw  = (const float*)d_in[11];
    const float* qkvb  = (const float*)d_in[12];
    const float* ao1w  = (const float*)d_in[13];
    const float* ao1b  = (const float*)d_in[14];
    const float* ao2w  = (const float*)d_in[15];
    const float* ao2b  = (const float*)d_in[16];
    const float* ln2sw = (const float*)d_in[17];
    const float* ln2bw = (const float*)d_in[18];
    const float* m1w   = (const float*)d_in[19];
    const float* m1b   = (const float*)d_in[20];
    const float* m2w   = (const float*)d_in[21];
    const float* m2b   = (const float*)d_in[22];
    const float* lnfsw = (const float*)d_in[23];
    const float* lnfbw = (const float*)d_in[24];
    const float* outw  = (const float*)d_in[25];
    const float* outb  = (const float*)d_in[26];
    float* out = (float*)d_out;

    char* p = (char*)d_ws;
    auto alloc = [&](size_t bytes) { void* r = (void*)p; p += (bytes + 255) & ~(size_t)255; return r; };
    float* h    = (float*)alloc(8192LL * 768 * 4);
    bf16*  hn   = (bf16*) alloc(8192LL * 768 * 2);
    bf16*  q    = (bf16*) alloc(8192LL * 768 * 2);
    bf16*  kbuf = (bf16*) alloc(8192LL * 768 * 2);
    bf16*  vbuf = (bf16*) alloc(8192LL * 768 * 2);   // V straight [B*S, 768]
    bf16*  vmT  = (bf16*) alloc(8192LL * 768 * 2);   // (V@Wm^T)^T per batch [B,768,1024]
    bf16*  P    = (bf16*) alloc(8LL * 1024 * 1024 * 2);
    bf16*  mb   = (bf16*) alloc(8192LL * 3072 * 2);
    bf16*  wout = (bf16*) alloc(1024LL * 768 * 2);
    bf16*  wmA  = (bf16*) alloc(12LL * 768 * 768 * 2);   // merged o2@o1, bf16
    float* bmA  = (float*)alloc(12LL * 768 * 4);         // merged o-bias
    float* s1   = (float*)alloc(12LL * 8 * 768 * 4);
    float* b1   = (float*)alloc(12LL * 8 * 768 * 4);
    float* s2   = (float*)alloc(12LL * 8 * 768 * 4);
    float* b2   = (float*)alloc(12LL * 8 * 768 * 4);
    float* sf   = (float*)alloc(8LL * 768 * 4);
    float* bfb  = (float*)alloc(8LL * 768 * 4);

    size_t base_needed = (size_t)(p - (char*)d_ws);
    if (base_needed + 16LL * 1024 * 1024 > ws_size) {
        fill_k<<<(out_size + 255) / 256, 256, 0, stream>>>(out, out_size, 1e9f);
        return;
    }

    const long long SZ_QKV = 2304LL * 768, SZ_O = 768LL * 768, SZ_M = 3072LL * 768;
    size_t all_bytes = (size_t)(12 * (SZ_QKV + 2 * SZ_M)) * 2;
    bool allw = ((size_t)(p - (char*)d_ws) + all_bytes + 4096 <= ws_size);

    bf16 *wqkvA, *wm1A, *wm2A;
    if (allw) {
        wqkvA = (bf16*)alloc(12 * SZ_QKV * 2);
        wm1A  = (bf16*)alloc(12 * SZ_M * 2);
        wm2A  = (bf16*)alloc(12 * SZ_M * 2);
    } else {
        wqkvA = (bf16*)alloc(SZ_QKV * 2);
        wm1A  = (bf16*)alloc(SZ_M * 2);
        wm2A  = (bf16*)alloc(SZ_M * 2);
    }

    // one-time scratch aliased onto regions unused until the layer loop:
    bf16*  xbf   = (bf16*)P;
    bf16*  dwbf  = (bf16*)P + 524288;
    bf16*  wo2bf = (bf16*)P + 1048576;
    float* xe    = (float*)mb;
    bf16*  o1t   = mb + 12582912;

    // --- one-time precompute ---
    cvt_bf16_k<<<1024 * 768 / 4 / 256, 256, 0, stream>>>(outw, wout, 1024 * 768 / 4);
    cond_proj_k<<<(12 * 8 * 768 + 255) / 256, 256, 0, stream>>>(label, ln1sw, ln1bw, s1, b1, 12 * 8 * 768);
    cond_proj_k<<<(12 * 8 * 768 + 255) / 256, 256, 0, stream>>>(label, ln2sw, ln2bw, s2, b2, 12 * 8 * 768);
    cond_proj_k<<<(8 * 768 + 255) / 256, 256, 0, stream>>>(label, lnfsw, lnfbw, sf, bfb, 8 * 768);

    if (allw) {
        cvt_bf16_k<<<(int)(12 * SZ_QKV / 4 / 256), 256, 0, stream>>>(qkvw, wqkvA, (int)(12 * SZ_QKV / 4));
        cvt_bf16_k<<<(int)(12 * SZ_M / 4 / 256),   256, 0, stream>>>(m1w,  wm1A,  (int)(12 * SZ_M / 4));
        cvt_bf16_k<<<(int)(12 * SZ_M / 4 / 256),   256, 0, stream>>>(m2w,  wm2A,  (int)(12 * SZ_M / 4));
    }

    // merged out-proj: Wm[l] = o2[l] @ o1[l]  (bf16), bm[l] = o2[l]@o1b[l] + o2b[l]
    cvt_bf16_k<<<(int)(12 * SZ_O / 4 / 256), 256, 0, stream>>>(ao2w, wo2bf, (int)(12 * SZ_O / 4));
    transpose_cvt_k<<<dim3(24, 24, 12), 256, 0, stream>>>(ao1w, o1t, 768);
    gemm_k<M_WM><<<dim3(6, 6, 12), 256, 49152, stream>>>(
        wo2bf, o1t, 768, 768, 768, SZ_O, SZ_O, SZ_O,
        nullptr, wmA, nullptr, nullptr, nullptr, nullptr);
    bias_merge_k<<<(12 * 768 + 3) / 4, 256, 0, stream>>>(ao2w, ao1b, ao2b, bmA, 12 * 768);

    // embed: x->bf16, xe = x @ dw^T + db (fp32), then shift+pos
    cvt_bf16_k<<<8192 * 64 / 4 / 256, 256, 0, stream>>>(x, xbf, 8192 * 64 / 4);
    cvt_bf16_k<<<768 * 64 / 4 / 256, 256, 0, stream>>>(dw, dwbf, 768 * 64 / 4);
    gemm_k<M_OUT><<<dim3(64, 6, 1), 256, 49152, stream>>>(
        xbf, dwbf, 8192, 768, 64, 0, 0, 0, db, nullptr, xe, nullptr, nullptr, nullptr);
    shift_pos_k<<<dim3(1024, 8), 256, 0, stream>>>(xe, sos, p0, p1, p2, h);

    for (int l = 0; l < 12; ++l) {
        bf16 *wqkv, *wm1, *wm2;
        if (allw) {
            wqkv = wqkvA + (long long)l * SZ_QKV;
            wm1  = wm1A  + (long long)l * SZ_M;
            wm2  = wm2A  + (long long)l * SZ_M;
        } else {
            wqkv = wqkvA; wm1 = wm1A; wm2 = wm2A;
            cvt_bf16_k<<<(int)(SZ_QKV / 4 / 256), 256, 0, stream>>>(qkvw + (long long)l * SZ_QKV, wqkv, (int)(SZ_QKV / 4));
            cvt_bf16_k<<<(int)(SZ_M / 4 / 256),   256, 0, stream>>>(m1w  + (long long)l * SZ_M,   wm1,  (int)(SZ_M / 4));
            cvt_bf16_k<<<(int)(SZ_M / 4 / 256),   256, 0, stream>>>(m2w  + (long long)l * SZ_M,   wm2,  (int)(SZ_M / 4));
        }

        cond_ln_k<<<dim3(256, 8), 256, 0, stream>>>(h, s1 + (long long)l * 6144, b1 + (long long)l * 6144, hn);

        gemm_k<M_QKV><<<dim3(64, 18, 1), 256, 49152, stream>>>(
            hn, wqkv, 8192, 2304, 768, 0, 0, 0,
            qkvb + (long long)l * 2304, nullptr, nullptr, q, kbuf, vbuf);

        // Vm = V @ Wm^T  (replaces the post-PV out-proj, by associativity);
        // epilogue writes transposed per batch: vmT[b, dout, s]
        gemm64_k<M_VMT><<<dim3(128, 6, 1), 256, 49152, stream>>>(
            vbuf, wmA + (long long)l * SZ_O, 8192, 768, 768, 0, 0, 0,
            nullptr, vmT, nullptr);

        gemm64_k<M_SCORES><<<dim3(16, 8, 8), 256, 49152, stream>>>(
            q, kbuf, 1024, 1024, 768, 1024LL * 768, 1024LL * 768, 1024LL * 1024,
            nullptr, P, nullptr);

        softmax_k<<<dim3(256, 8), 256, 0, stream>>>(P);

        // h += P @ Vm + bm   (attn output + merged out-proj + residual, fused)
        gemm64_k<M_PVRESID><<<dim3(16, 6, 8), 256, 49152, stream>>>(
            P, vmT, 1024, 768, 1024, 1024LL * 1024, 768LL * 1024, 0,
            bmA + (long long)l * 768, nullptr, h);

        cond_ln_k<<<dim3(256, 8), 256, 0, stream>>>(h, s2 + (long long)l * 6144, b2 + (long long)l * 6144, hn);

        gemm_k<M_GELU><<<dim3(64, 24, 1), 256, 49152, stream>>>(
            hn, wm1, 8192, 3072, 768, 0, 0, 0,
            m1b + (long long)l * 3072, mb, nullptr, nullptr, nullptr, nullptr);

        gemm64_k<M_RESID><<<dim3(128, 6, 1), 256, 49152, stream>>>(
            mb, wm2, 8192, 768, 3072, 0, 0, 0,
            m2b + (long long)l * 768, nullptr, h);
    }

    cond_ln_k<<<dim3(256, 8), 256, 0, stream>>>(h, sf, bfb, hn);
    gemm64_k<M_OUT><<<dim3(128, 8, 1), 256, 49152, stream>>>(
        hn, wout, 8192, 1024, 768, 0, 0, 0,
        outb, nullptr, out);
}